// Round 6
// baseline (1127.753 us; speedup 1.0000x reference)
//
#include <hip/hip_runtime.h>

// Problem constants (from reference)
#define NODES  50000
#define EDGES  800000
#define NGRAPH 512

// short-element offsets inside the canonical bf16 weight buffer (wbuf).
// All W matrices are stored TRANSPOSED: Wt[j][k] (128 rows x CH cols), so the
// MFMA B-fragment (8 consecutive k for fixed j) is a contiguous 16B load.
#define OFF_WL0T 0         // [128][64]
#define OFF_WR0T 8192      // [128][64]
#define OFF_WLT  16384     // 11 x [128][128]
#define OFF_WRT  196608    // 11 x [128][128]
#define OFF_B0   376832    // 128
#define OFF_B    376960    // 11*128
#define OFF_HW   378368    // 128*2 (row-major, as input)
#define OFF_HB   378624    // 2
#define WBUF_N   378626

typedef __attribute__((ext_vector_type(8))) short bf16x8;
typedef __attribute__((ext_vector_type(4))) float f32x4;

// ---------- bf16 helpers (internal compute fp32) ----------
__device__ __forceinline__ float bflo(unsigned int u) {
    union { unsigned int i; float f; } c; c.i = u << 16; return c.f;
}
__device__ __forceinline__ float bfhi(unsigned int u) {
    union { unsigned int i; float f; } c; c.i = u & 0xffff0000u; return c.f;
}
__device__ __forceinline__ float bf2f(unsigned short u) {
    union { unsigned int i; float f; } c; c.i = ((unsigned int)u) << 16; return c.f;
}
__device__ __forceinline__ unsigned short f2bf(float f) {
    union { float f; unsigned int i; } c; c.f = f;
    unsigned int u = c.i;
    u = (u + 0x7fffu + ((u >> 16) & 1u)) >> 16;   // round-to-nearest-even
    return (unsigned short)u;
}

// counted vmcnt wait (T4): literal-folded switch; sched_barrier pins the
// following ds_read behind the wait (rule #18 analog for LDS-DMA consume).
__device__ __forceinline__ void waitv(int n) {
    switch (n) {
    case 0: asm volatile("s_waitcnt vmcnt(0)" ::: "memory"); break;
    case 1: asm volatile("s_waitcnt vmcnt(1)" ::: "memory"); break;
    case 2: asm volatile("s_waitcnt vmcnt(2)" ::: "memory"); break;
    case 3: asm volatile("s_waitcnt vmcnt(3)" ::: "memory"); break;
    case 4: asm volatile("s_waitcnt vmcnt(4)" ::: "memory"); break;
    case 5: asm volatile("s_waitcnt vmcnt(5)" ::: "memory"); break;
    case 6: asm volatile("s_waitcnt vmcnt(6)" ::: "memory"); break;
    default: asm volatile("s_waitcnt vmcnt(7)" ::: "memory"); break;
    }
    __builtin_amdgcn_sched_barrier(0);
}

// ---------- block-local dtype sniff: bf16 inputs -> 0, fp32 inputs -> 1 ----------
// 64-lane shuffle reduction: MUST be called by ALL lanes of a wave, i.e. before
// any divergent early-return (round-10 bug).
__device__ __forceinline__ int detect_mode(const unsigned int* __restrict__ xu) {
    int bad = 0;
    for (int i = (threadIdx.x & 63); i < 512; i += 64) {
        const unsigned int u = xu[i];
        if (!(fabsf(bflo(u)) < 1e4f)) bad++;   // also catches NaN
        if (!(fabsf(bfhi(u)) < 1e4f)) bad++;
    }
#pragma unroll
    for (int off = 32; off; off >>= 1) bad += __shfl_down(bad, off);
    bad = __shfl(bad, 0);
    return (bad > 16) ? 1 : 0;
}

// ---------- repack weights into canonical bf16 buffer (W's transposed) ----------
__global__ __launch_bounds__(256) void k_cvt_w(const void* xin,
                                               const void* s0, const void* s1, const void* s2,
                                               const void* s3, const void* s4, const void* s5,
                                               const void* s6, const void* s7,
                                               unsigned short* __restrict__ wbuf) {
    const int m = detect_mode((const unsigned int*)xin);   // before any divergent return
    const int i = blockIdx.x * 256 + threadIdx.x;
    if (i >= WBUF_N) return;
    const void* src; int local;
    if (i < OFF_WR0T) {                       // Wl0^T: out(j,k) <- in(k,j), in = 64x128
        const int j = i >> 6, k = i & 63;
        src = s0; local = k * 128 + j;
    } else if (i < OFF_WLT) {                 // Wr0^T
        const int t = i - OFF_WR0T, j = t >> 6, k = t & 63;
        src = s1; local = k * 128 + j;
    } else if (i < OFF_WRT) {                 // Wl^T: 11 x (out(j,k) <- in(k,j)), in = 128x128
        const int t = i - OFF_WLT, l = t >> 14, r = t & 16383, j = r >> 7, k = r & 127;
        src = s3; local = (l << 14) + k * 128 + j;
    } else if (i < OFF_B0) {                  // Wr^T
        const int t = i - OFF_WRT, l = t >> 14, r = t & 16383, j = r >> 7, k = r & 127;
        src = s4; local = (l << 14) + k * 128 + j;
    } else if (i < OFF_B) {
        src = s2; local = i - OFF_B0;         // b0
    } else if (i < OFF_HW) {
        src = s5; local = i - OFF_B;          // b
    } else if (i < OFF_HB) {
        src = s6; local = i - OFF_HW;         // head_W
    } else {
        src = s7; local = i - OFF_HB;         // head_b
    }
    wbuf[i] = m ? f2bf(((const float*)src)[local]) : ((const unsigned short*)src)[local];
}

// ---------- x -> canonical bf16 (N x 64) + zero deg/gsum/gcnt/dummy rows ----------
// Dummy row trick: CSR is padded per-node to a multiple of 8 with index =
// NODES, which must point at an all-zero feature row so padded gathers add
// exactly 0.0f. hA's 64-wide dummy (conv 0) and both buffers' 128-wide
// dummies (convs 1..11; GEMM never writes row NODES so they stay zero).
#define CVT_BLOCKS 1563    // ceil(NODES*64/8 / 256)
#define ZERO_BASE  (NODES + NGRAPH * 128 + NGRAPH)
#define ZERO_WORDS (ZERO_BASE + 160)   // + hA64 dummy (32w) + hA128 (64w) + hB128 (64w)
__global__ __launch_bounds__(256) void k_cvt_x(const void* __restrict__ xin,
                                               unsigned short* __restrict__ hx,
                                               unsigned short* __restrict__ hB,
                                               int* __restrict__ deg,
                                               float* __restrict__ gsum,
                                               float* __restrict__ gcnt) {
    if (blockIdx.x >= CVT_BLOCKS) {           // zeroing tail (block-uniform branch)
        const int i = (blockIdx.x - CVT_BLOCKS) * 256 + threadIdx.x;
        if (i < NODES) deg[i] = 0;
        else if (i < NODES + NGRAPH * 128) gsum[i - NODES] = 0.f;
        else if (i < ZERO_BASE) gcnt[i - NODES - NGRAPH * 128] = 0.f;
        else if (i < ZERO_BASE + 32)
            ((unsigned int*)(hx + (size_t)NODES * 64))[i - ZERO_BASE] = 0u;
        else if (i < ZERO_BASE + 96)
            ((unsigned int*)(hx + (size_t)NODES * 128))[i - ZERO_BASE - 32] = 0u;
        else if (i < ZERO_WORDS)
            ((unsigned int*)(hB + (size_t)NODES * 128))[i - ZERO_BASE - 96] = 0u;
        return;
    }
    const int m = detect_mode((const unsigned int*)xin);   // before divergent return
    const int i = blockIdx.x * 256 + threadIdx.x;   // groups of 8 elements
    if (i >= NODES * 64 / 8) return;
    if (m == 0) {
        ((uint4*)hx)[i] = ((const uint4*)xin)[i];
    } else {
        const float4* f = (const float4*)xin;
        const float4 a = f[2 * i], b = f[2 * i + 1];
        const unsigned int p0 = f2bf(a.x) | ((unsigned int)f2bf(a.y) << 16);
        const unsigned int p1 = f2bf(a.z) | ((unsigned int)f2bf(a.w) << 16);
        const unsigned int p2 = f2bf(b.x) | ((unsigned int)f2bf(b.y) << 16);
        const unsigned int p3 = f2bf(b.z) | ((unsigned int)f2bf(b.w) << 16);
        ((uint4*)hx)[i] = make_uint4(p0, p1, p2, p3);
    }
}

// ---------- CSR build (by dst), 8-aligned padded rows ----------
__global__ __launch_bounds__(256) void k_count(const int* __restrict__ ei,
                                               int* __restrict__ deg) {
    const int e = blockIdx.x * 256 + threadIdx.x;
    if (e < EDGES) {
        const int d = ei[EDGES + e];
        if ((unsigned)d < NODES) atomicAdd(&deg[d], 1);
    }
}

// scan over PADDED degrees: p = (d+7) & ~7
__global__ __launch_bounds__(1024) void k_scan_block(const int* __restrict__ deg,
                                                     int* __restrict__ tmp,
                                                     int* __restrict__ bsums) {
    __shared__ int s[1024];
    const int idx = blockIdx.x * 1024 + threadIdx.x;
    s[threadIdx.x] = (idx < NODES) ? ((deg[idx] + 7) & ~7) : 0;
    __syncthreads();
    for (int off = 1; off < 1024; off <<= 1) {
        int v = (threadIdx.x >= off) ? s[threadIdx.x - off] : 0;
        __syncthreads();
        s[threadIdx.x] += v;
        __syncthreads();
    }
    if (idx < NODES) tmp[idx] = s[threadIdx.x];
    if (threadIdx.x == 1023) bsums[blockIdx.x] = s[1023];
}

__global__ void k_scan_sums(int* __restrict__ bsums, int nb) {
    if (threadIdx.x == 0 && blockIdx.x == 0) {
        int acc = 0;
        for (int i = 0; i < nb; ++i) { int v = bsums[i]; bsums[i] = acc; acc += v; }
    }
}

// Emits per-node 16B descriptor {start, padded_deg, inv_deg_bits, 0} so the
// gather's node setup is ONE broadcast load instead of 3 dependent loads.
__global__ __launch_bounds__(1024) void k_scan_fin(const int* __restrict__ deg,
                                                   const int* __restrict__ tmp,
                                                   const int* __restrict__ bsums,
                                                   int* __restrict__ row_ptr,
                                                   int* __restrict__ cursor,
                                                   uint4* __restrict__ descs,
                                                   unsigned short* __restrict__ csr_src) {
    const int idx = blockIdx.x * 1024 + threadIdx.x;
    if (idx >= NODES) return;
    const int incl = tmp[idx] + bsums[blockIdx.x];      // padded inclusive scan
    const int d = deg[idx];
    const int p = (d + 7) & ~7;
    const int start = incl - p;
    row_ptr[idx + 1] = incl;
    cursor[idx] = start;
    const float iv = (d > 0) ? (1.0f / (float)d) : 0.0f;
    descs[idx] = make_uint4((unsigned)start, (unsigned)p, __float_as_uint(iv), 0u);
    for (int i = d; i < p; ++i) csr_src[start + i] = (unsigned short)NODES;  // pad -> zero row
    if (idx == 0) row_ptr[0] = 0;
}

// plain scatter store (round-11: atomicExch regressed; WRITE amplification
// structural). csr entries ushort (src < 65536).
__global__ __launch_bounds__(256) void k_fill(const int* __restrict__ ei,
                                              int* __restrict__ cursor,
                                              unsigned short* __restrict__ csr_src) {
    const int e = blockIdx.x * 256 + threadIdx.x;
    if (e < EDGES) {
        const int d = ei[EDGES + e];
        if ((unsigned)d < NODES) {
            const int p = atomicAdd(&cursor[d], 1);
            csr_src[p] = (unsigned short)ei[e];
        }
    }
}

// ws-too-small sentinel: absmax will read ~(1000 + ws_MB)
__global__ __launch_bounds__(256) void k_ws_stamp(unsigned short* __restrict__ outp, float v) {
    const int t = blockIdx.x * 256 + threadIdx.x;
    if (t < NGRAPH * 2) outp[t] = f2bf(v);
}

// ---------- FUSED SAGE layer: out = act(mean_agg(h) @ Wl + h @ Wr + b) ----------
// Round-17 restructure: LDS-ring async gather (global_load_lds).
// Evidence r1-r5: hipcc never holds >1 gather batch of payload in VGPRs
// (60/48/32/64-spill/60), so per-wave in-flight bytes stayed ~1 batch and the
// gather ran latency-serial (~46-52 us/layer at constant FETCH ~80MB).
// global_load_lds removes payload from the register file entirely:
//   * depth R=8 ring of 1KB slots per wave (64 lanes x 16B per instruction =
//     4 edge-rows @CH=128, 8 @CH=64); counted vmcnt(7) in steady state (T3/T4,
//     never 0 in-loop); sustained in-flight ~8KB/wave, ~96KB/CU (3 blocks/CU).
//   * per-node setup = ONE 16B descriptor load {start,pdeg,inv}.
//   * indices via double-buffered register strips + __shfl (no dependent
//     index load on the critical path; strip prefetched LPN batches early so
//     compiler's auto-wait is a no-op vmcnt(LPN)).
//   * groups shorter than the wave-max consume dummy zero-row batches: +0.0f
//     exactly -> accumulation order & values BIT-IDENTICAL to r2-r5.
// Phase 2 (MFMA) unchanged: 4 waves; wave w owns cols n0=w*32 over 32 rows;
// acc[2][2]; A half-0 from LDS aggT, half-1 = h rows from global.
// mfma_f32_16x16x32_bf16 layouts (m89/m120-verified):
//   A-frag: lane holds A[m=lane&15][k=quad*8+j]; B-frag: B[k=quad*8+j][n=lane&15]
//   C/D: lane reg r holds D[row=quad*4+r][col=lane&15]
// act: 0=none 1=relu 2=leaky(0.01)
template <int CH>
__global__ __launch_bounds__(256, 3) void k_fused(const unsigned short* __restrict__ h,   // N x CH (+ zero row)
                                                  const unsigned short* __restrict__ csr_src,
                                                  const uint4* __restrict__ descs,
                                                  const unsigned short* __restrict__ Wt1, // [128][CH]
                                                  const unsigned short* __restrict__ Wt2, // [128][CH]
                                                  const unsigned short* __restrict__ bias,
                                                  unsigned short* __restrict__ outp,      // N x 128
                                                  int act) {
    constexpr int R      = 8;                 // ring depth (slots of 1KB)
    constexpr int LPN    = CH / 8;            // lanes per node-row (16 or 8)
    constexpr int GROUPS = 64 / LPN;          // node-rows gathered per inst (4 or 8)
    constexpr int SETS   = 8 / GROUPS;        // 8 nodes/wave total (2 or 1 sets)
    constexpr int LSTR   = CH + 8;            // padded LDS stride (shorts)
    constexpr int MT     = 2;                 // m-tiles in GEMM (32 rows)
    __shared__ uint4 ring[4][R][64];          // 32 KB: per-wave async staging
    __shared__ unsigned short aggT[32][LSTR];

    const int wave = threadIdx.x >> 6;
    const int lane = threadIdx.x & 63;

    // ---- phase 1: mean-aggregate this block's 32 rows into LDS ----
    {
        const int cl = lane & (LPN - 1);      // 16B chunk within the node row
#pragma unroll
        for (int set = 0; set < SETS; ++set) {
            const int g    = lane / LPN;                      // group = node slot
            const int rl   = wave * 8 + set * GROUPS + g;     // local row 0..31
            const int node = blockIdx.x * 32 + rl;
            const int dn   = (node < NODES) ? node : 0;
            const uint4 dsc = descs[dn];
            const int   start_l = (int)dsc.x;
            const int   pdeg_l  = (node < NODES) ? (int)dsc.y : 0;
            const float inv_l   = (node < NODES) ? __uint_as_float(dsc.z) : 0.f;

            // wave-uniform batch count = max over this wave's groups
            int B = pdeg_l;
#pragma unroll
            for (int off = LPN; off < 64; off <<= 1) {
                const int o = __shfl_xor(B, off);
                B = (o > B) ? o : B;
            }

            // index strips: lane cl holds edge s*LPN+cl of its group
            int vcur = (int)csr_src[start_l + cl];
            int vnxt = (int)csr_src[start_l + LPN + cl];

            float c0 = 0.f, c1 = 0.f, c2 = 0.f, c3 = 0.f;
            float c4 = 0.f, c5 = 0.f, c6 = 0.f, c7 = 0.f;

            auto issue = [&](int p) {
                if (p > 0 && (p & (LPN - 1)) == 0) {          // rotate strips
                    vcur = vnxt;
                    vnxt = (int)csr_src[start_l + p + LPN + cl];
                }
                const int srcl = (lane & ~(LPN - 1)) | (p & (LPN - 1));
                int idx = __shfl(vcur, srcl);
                if (p >= pdeg_l) idx = NODES;                 // dummy zero row
                const unsigned short* ga = h + (size_t)idx * CH + cl * 8;
                __builtin_amdgcn_global_load_lds(
                    (const __attribute__((address_space(1))) unsigned int*)ga,
                    (__attribute__((address_space(3))) unsigned int*)&ring[wave][p & (R - 1)][0],
                    16, 0, 0);
            };

            const int Pn = (B < R) ? B : R;
            for (int p = 0; p < Pn; ++p) issue(p);            // prologue

            int b = 0;
            for (; b + R < B; ++b) {                          // steady: vmcnt(R-1)
                waitv(R - 1);
                const uint4 q = ring[wave][b & (R - 1)][lane];
                __builtin_amdgcn_sched_barrier(0);
                issue(b + R);
                c0 += bflo(q.x); c1 += bfhi(q.x);
                c2 += bflo(q.y); c3 += bfhi(q.y);
                c4 += bflo(q.z); c5 += bfhi(q.z);
                c6 += bflo(q.w); c7 += bfhi(q.w);
            }
            for (; b < B; ++b) {                              // drain tail
                waitv(B - 1 - b);
                const uint4 q = ring[wave][b & (R - 1)][lane];
                c0 += bflo(q.x); c1 += bfhi(q.x);
                c2 += bflo(q.y); c3 += bfhi(q.y);
                c4 += bflo(q.z); c5 += bfhi(q.z);
                c6 += bflo(q.w); c7 += bfhi(q.w);
            }

            c0 *= inv_l; c1 *= inv_l; c2 *= inv_l; c3 *= inv_l;
            c4 *= inv_l; c5 *= inv_l; c6 *= inv_l; c7 *= inv_l;
            uint4 o;     // rows >= NODES stay exactly zero (never NaN into MFMA)
            o.x = f2bf(c0) | ((unsigned int)f2bf(c1) << 16);
            o.y = f2bf(c2) | ((unsigned int)f2bf(c3) << 16);
            o.z = f2bf(c4) | ((unsigned int)f2bf(c5) << 16);
            o.w = f2bf(c6) | ((unsigned int)f2bf(c7) << 16);
            *(uint4*)&aggT[rl][cl * 8] = o;
        }
    }
    __syncthreads();

    // ---- phase 2: MFMA ----
    const int quad = lane >> 4;
    const int l16  = lane & 15;
    const int n0   = wave * 32;                // this wave's column origin
    const int m0   = blockIdx.x * 32;
    int rowH[MT];
#pragma unroll
    for (int mt = 0; mt < MT; ++mt) {
        int rr = m0 + mt * 16 + l16;           // global rows for the h@Wr half
        if (rr >= NODES) rr = NODES - 1;       // clamped rows feed MFMA, never stored
        rowH[mt] = rr;
    }

    constexpr int KC = CH / 32;
    constexpr int NS = 2 * KC;

    auto loadA = [&](int s, int mt) -> bf16x8 {
        if (s < KC)
            return *(const bf16x8*)&aggT[mt * 16 + l16][s * 32 + quad * 8];
        return *(const bf16x8*)(h + (size_t)rowH[mt] * CH + (s - KC) * 32 + quad * 8);
    };
    auto loadB = [&](int s, int nt) -> bf16x8 {
        const unsigned short* W = (s < KC) ? Wt1 : Wt2;
        const int kc = (s < KC) ? s : s - KC;
        return *(const bf16x8*)(W + (size_t)(n0 + nt * 16 + l16) * CH + kc * 32 + quad * 8);
    };

    f32x4 acc[MT][2];
#pragma unroll
    for (int mt = 0; mt < MT; ++mt)
#pragma unroll
        for (int nt = 0; nt < 2; ++nt) acc[mt][nt] = (f32x4){0.f, 0.f, 0.f, 0.f};

    bf16x8 a[MT], b[2];
#pragma unroll
    for (int mt = 0; mt < MT; ++mt) a[mt] = loadA(0, mt);
#pragma unroll
    for (int nt = 0; nt < 2; ++nt) b[nt] = loadB(0, nt);

#pragma unroll
    for (int s = 0; s < NS; ++s) {
        bf16x8 na[MT], nb[2];
        if (s + 1 < NS) {                      // issue next step's loads first
#pragma unroll
            for (int mt = 0; mt < MT; ++mt) na[mt] = loadA(s + 1, mt);
#pragma unroll
            for (int nt = 0; nt < 2; ++nt) nb[nt] = loadB(s + 1, nt);
        }
#pragma unroll
        for (int mt = 0; mt < MT; ++mt)
#pragma unroll
            for (int nt = 0; nt < 2; ++nt)
                acc[mt][nt] = __builtin_amdgcn_mfma_f32_16x16x32_bf16(a[mt], b[nt], acc[mt][nt], 0, 0, 0);
        if (s + 1 < NS) {
#pragma unroll
            for (int mt = 0; mt < MT; ++mt) a[mt] = na[mt];
#pragma unroll
            for (int nt = 0; nt < 2; ++nt) b[nt] = nb[nt];
        }
    }

#pragma unroll
    for (int nt = 0; nt < 2; ++nt) {
        const float bj = bf2f(bias[n0 + nt * 16 + l16]);
#pragma unroll
        for (int mt = 0; mt < MT; ++mt) {
#pragma unroll
            for (int r = 0; r < 4; ++r) {
                const int row = m0 + mt * 16 + quad * 4 + r;
                if (row < NODES) {
                    float v = acc[mt][nt][r] + bj;
                    if (act == 1) v = fmaxf(v, 0.f);
                    else if (act == 2) v = v > 0.f ? v : 0.01f * v;
                    outp[(size_t)row * 128 + n0 + nt * 16 + l16] = f2bf(v);
                }
            }
        }
    }
}

// ---------- segmented global mean pool (batch_idx sorted) ----------
__global__ __launch_bounds__(512) void k_pool(const unsigned short* __restrict__ h,
                                              const int* __restrict__ batch,
                                              float* __restrict__ gsum,
                                              float* __restrict__ gcnt) {
    const int c = threadIdx.x & 127;
    const int sg = threadIdx.x >> 7;            // 0..3
    const int n0 = blockIdx.x * 128;
    float s = 0.f;
    int cnt = 0, gprev = -1;
#pragma unroll 4
    for (int i = 0; i < 32; ++i) {
        const int n = n0 + i * 4 + sg;
        if (n >= NODES) break;
        int g = batch[n];
        if ((unsigned)g >= NGRAPH) g = (gprev < 0) ? 0 : gprev;
        if (g != gprev) {
            if (gprev >= 0) {
                atomicAdd(&gsum[(size_t)gprev * 128 + c], s);
                if (c == 0) atomicAdd(&gcnt[gprev], (float)cnt);
            }
            s = 0.f; cnt = 0; gprev = g;
        }
        s += bf2f(h[(size_t)n * 128 + c]);
        cnt++;
    }
    if (gprev >= 0) {
        atomicAdd(&gsum[(size_t)gprev * 128 + c], s);
        if (c == 0) atomicAdd(&gcnt[gprev], (float)cnt);
    }
}

// ---------- head: out = pooled @ head_W + head_b (dtype-adaptive store) ----------
__global__ __launch_bounds__(256) void k_head(const float* __restrict__ gsum,
                                              const float* __restrict__ gcnt,
                                              const unsigned short* __restrict__ wbuf,
                                              const void* __restrict__ xin,
                                              void* __restrict__ outp) {
    const int m = detect_mode((const unsigned int*)xin);   // before any divergent return
    const int t = blockIdx.x * 256 + threadIdx.x;
    if (t >= NGRAPH * 2) return;
    const int g = t >> 1, o = t & 1;
    const float inv = 1.0f / fmaxf(gcnt[g], 1.0f);
    float s = bf2f(wbuf[OFF_HB + o]);
    for (int c = 0; c < 128; ++c)
        s += gsum[(size_t)g * 128 + c] * inv * bf2f(wbuf[OFF_HW + c * 2 + o]);
    if (m) ((float*)outp)[t] = s;
    else ((unsigned short*)outp)[t] = f2bf(s);
}

extern "C" void kernel_launch(void* const* d_in, const int* in_sizes, int n_in,
                              void* d_out, int out_size, void* d_ws, size_t ws_size,
                              hipStream_t stream) {
    const void* x     = d_in[0];
    const int*  ei    = (const int*)d_in[1];
    const int*  batch = (const int*)d_in[2];

    // ---- workspace carve-up (~30 MB; ws_size measured 256 MB in round 8) ----
    char* p = (char*)d_ws;
    auto alloc = [&](size_t bytes) -> void* {
        void* r = (void*)p;
        p += (bytes + 255) & ~(size_t)255;
        return r;
    };
    // +128 shorts: zero dummy row (index NODES) for padded-CSR gathers
    unsigned short* hA   = (unsigned short*)alloc(((size_t)NODES * 128 + 128) * 2);
    unsigned short* hB   = (unsigned short*)alloc(((size_t)NODES * 128 + 128) * 2);
    unsigned short* wbuf = (unsigned short*)alloc((size_t)(WBUF_N + 14) * 2);
    int*   deg     = (int*)alloc((size_t)NODES * 4);
    int*   tmp     = (int*)alloc((size_t)NODES * 4);
    int*   row_ptr = (int*)alloc((size_t)(NODES + 1) * 4);
    int*   cursor  = (int*)alloc((size_t)NODES * 4);
    uint4* descs   = (uint4*)alloc((size_t)NODES * 16);
    unsigned short* csr_src = (unsigned short*)alloc((size_t)(EDGES + 8 * NODES + 256) * 2); // padded + strip slack
    int*   bsums   = (int*)alloc(64 * 4);
    float* gsum    = (float*)alloc((size_t)NGRAPH * 128 * 4);
    float* gcnt    = (float*)alloc((size_t)NGRAPH * 4);
    const size_t need = (size_t)(p - (char*)d_ws);
    (void)in_sizes; (void)n_in; (void)out_size;

    if (ws_size < need) {
        k_ws_stamp<<<4, 256, 0, stream>>>((unsigned short*)d_out,
                                          1000.0f + (float)(ws_size >> 20));
        return;
    }

    // setup: weight repack (mode sniffed block-locally), x convert + zero tail
    const int zeroBlocks = (ZERO_WORDS + 255) / 256;
    k_cvt_w<<<(WBUF_N + 255) / 256, 256, 0, stream>>>(x, d_in[3], d_in[4], d_in[5], d_in[6],
                                                      d_in[7], d_in[8], d_in[9], d_in[10], wbuf);
    k_cvt_x<<<CVT_BLOCKS + zeroBlocks, 256, 0, stream>>>(x, hA, hB, deg, gsum, gcnt);

    // CSR build (by dst), 8-aligned padded rows + per-node descriptors
    const int nbScan = (NODES + 1023) / 1024;   // 49
    k_count<<<(EDGES + 255) / 256, 256, 0, stream>>>(ei, deg);
    k_scan_block<<<nbScan, 1024, 0, stream>>>(deg, tmp, bsums);
    k_scan_sums<<<1, 64, 0, stream>>>(bsums, nbScan);
    k_scan_fin<<<nbScan, 1024, 0, stream>>>(deg, tmp, bsums, row_ptr, cursor, descs, csr_src);
    k_fill<<<(EDGES + 255) / 256, 256, 0, stream>>>(ei, cursor, csr_src);

    const int gemmGrid = (NODES + 31) / 32;      // 1563 (32 rows per block)

    // conv 0: 64 -> 128, ReLU. x in hA (N x 64); fused agg+GEMM -> hB.
    k_fused<64><<<gemmGrid, 256, 0, stream>>>(hA, csr_src, descs,
                                              wbuf + OFF_WL0T, wbuf + OFF_WR0T,
                                              wbuf + OFF_B0, hB, 1);

    // convs 1..11: 128 -> 128, ping-pong hB <-> hA
    unsigned short* cur = hB;
    unsigned short* nxt = hA;
    for (int i = 0; i < 11; ++i) {
        const int ci = i + 1;
        const int act = ((ci + 1) % 4 != 0) ? 1 : ((ci == 3 || ci == 7) ? 2 : 0);
        k_fused<128><<<gemmGrid, 256, 0, stream>>>(cur, csr_src, descs,
                                                   wbuf + OFF_WLT + (size_t)i * 128 * 128,
                                                   wbuf + OFF_WRT + (size_t)i * 128 * 128,
                                                   wbuf + OFF_B + (size_t)i * 128,
                                                   nxt, act);
        unsigned short* t = cur; cur = nxt; nxt = t;
    }

    // pool + head
    k_pool<<<(NODES + 127) / 128, 512, 0, stream>>>(cur, batch, gsum, gcnt);
    k_head<<<(NGRAPH * 2 + 255) / 256, 256, 0, stream>>>(gsum, gcnt, wbuf, x, d_out);
}

// Round 7
// 692.438 us; speedup vs baseline: 1.6287x; 1.6287x over previous
//
#include <hip/hip_runtime.h>

// Problem constants (from reference)
#define NODES  50000
#define EDGES  800000
#define NGRAPH 512

// short-element offsets inside the canonical bf16 weight buffer (wbuf).
// All W matrices are stored TRANSPOSED: Wt[j][k] (128 rows x CH cols), so the
// MFMA B-fragment (8 consecutive k for fixed j) is a contiguous 16B load.
#define OFF_WL0T 0         // [128][64]
#define OFF_WR0T 8192      // [128][64]
#define OFF_WLT  16384     // 11 x [128][128]
#define OFF_WRT  196608    // 11 x [128][128]
#define OFF_B0   376832    // 128
#define OFF_B    376960    // 11*128
#define OFF_HW   378368    // 128*2 (row-major, as input)
#define OFF_HB   378624    // 2
#define WBUF_N   378626

typedef __attribute__((ext_vector_type(8))) short bf16x8;
typedef __attribute__((ext_vector_type(4))) float f32x4;

// ---------- bf16 helpers (internal compute fp32) ----------
__device__ __forceinline__ float bflo(unsigned int u) {
    union { unsigned int i; float f; } c; c.i = u << 16; return c.f;
}
__device__ __forceinline__ float bfhi(unsigned int u) {
    union { unsigned int i; float f; } c; c.i = u & 0xffff0000u; return c.f;
}
__device__ __forceinline__ float bf2f(unsigned short u) {
    union { unsigned int i; float f; } c; c.i = ((unsigned int)u) << 16; return c.f;
}
__device__ __forceinline__ unsigned short f2bf(float f) {
    union { float f; unsigned int i; } c; c.f = f;
    unsigned int u = c.i;
    u = (u + 0x7fffu + ((u >> 16) & 1u)) >> 16;   // round-to-nearest-even
    return (unsigned short)u;
}

// ---------- block-local dtype sniff: bf16 inputs -> 0, fp32 inputs -> 1 ----------
// 64-lane shuffle reduction: MUST be called by ALL lanes of a wave, i.e. before
// any divergent early-return (round-10 bug).
__device__ __forceinline__ int detect_mode(const unsigned int* __restrict__ xu) {
    int bad = 0;
    for (int i = (threadIdx.x & 63); i < 512; i += 64) {
        const unsigned int u = xu[i];
        if (!(fabsf(bflo(u)) < 1e4f)) bad++;   // also catches NaN
        if (!(fabsf(bfhi(u)) < 1e4f)) bad++;
    }
#pragma unroll
    for (int off = 32; off; off >>= 1) bad += __shfl_down(bad, off);
    bad = __shfl(bad, 0);
    return (bad > 16) ? 1 : 0;
}

// ---------- fused setup: x-convert + zeroing + weight repack (range dispatch) ----
// Dummy row trick: CSR is padded per-node to a multiple of 8 with index =
// NODES, pointing at an all-zero feature row so padded gathers add exactly
// 0.0f. Zero list: deg, gsum, gcnt, hA64 dummy, hA128 dummy, hB128 dummy,
// bucketCur (round-18 binned CSR build).
#define CVT_BLOCKS 1563    // ceil(NODES*64/8 / 256)
#define ZB_GSUM  (NODES)
#define ZB_GCNT  (NODES + NGRAPH * 128)
#define ZB_D64   (NODES + NGRAPH * 128 + NGRAPH)
#define ZB_D128A (ZB_D64 + 32)
#define ZB_D128B (ZB_D64 + 96)
#define ZB_BCUR  (ZB_D64 + 160)
#define ZERO_WORDS (ZB_BCUR + 128)
#define ZERO_BLOCKS ((ZERO_WORDS + 255) / 256)     // 455
#define W_BLOCKS ((WBUF_N + 255) / 256)            // 1480
__global__ __launch_bounds__(256) void k_setup(const void* __restrict__ xin,
                                               const void* s0, const void* s1, const void* s2,
                                               const void* s3, const void* s4, const void* s5,
                                               const void* s6, const void* s7,
                                               unsigned short* __restrict__ wbuf,
                                               unsigned short* __restrict__ hx,
                                               unsigned short* __restrict__ hB,
                                               int* __restrict__ deg,
                                               float* __restrict__ gsum,
                                               float* __restrict__ gcnt,
                                               int* __restrict__ bucketCur) {
    if (blockIdx.x < CVT_BLOCKS) {            // ---- x -> bf16 canonical (N x 64)
        const int m = detect_mode((const unsigned int*)xin);   // before divergent return
        const int i = blockIdx.x * 256 + threadIdx.x;   // groups of 8 elements
        if (i >= NODES * 64 / 8) return;
        if (m == 0) {
            ((uint4*)hx)[i] = ((const uint4*)xin)[i];
        } else {
            const float4* f = (const float4*)xin;
            const float4 a = f[2 * i], b = f[2 * i + 1];
            const unsigned int p0 = f2bf(a.x) | ((unsigned int)f2bf(a.y) << 16);
            const unsigned int p1 = f2bf(a.z) | ((unsigned int)f2bf(a.w) << 16);
            const unsigned int p2 = f2bf(b.x) | ((unsigned int)f2bf(b.y) << 16);
            const unsigned int p3 = f2bf(b.z) | ((unsigned int)f2bf(b.w) << 16);
            ((uint4*)hx)[i] = make_uint4(p0, p1, p2, p3);
        }
        return;
    }
    if (blockIdx.x < CVT_BLOCKS + ZERO_BLOCKS) {   // ---- zeroing tail
        const int i = (blockIdx.x - CVT_BLOCKS) * 256 + threadIdx.x;
        if (i < ZB_GSUM) deg[i] = 0;
        else if (i < ZB_GCNT) gsum[i - ZB_GSUM] = 0.f;
        else if (i < ZB_D64) gcnt[i - ZB_GCNT] = 0.f;
        else if (i < ZB_D128A)
            ((unsigned int*)(hx + (size_t)NODES * 64))[i - ZB_D64] = 0u;
        else if (i < ZB_D128B)
            ((unsigned int*)(hx + (size_t)NODES * 128))[i - ZB_D128A] = 0u;
        else if (i < ZB_BCUR)
            ((unsigned int*)(hB + (size_t)NODES * 128))[i - ZB_D128B] = 0u;
        else if (i < ZERO_WORDS)
            bucketCur[i - ZB_BCUR] = 0;
        return;
    }
    // ---- weight repack (mode sniffed block-locally)
    const int m = detect_mode((const unsigned int*)xin);   // before any divergent return
    const int i = (blockIdx.x - CVT_BLOCKS - ZERO_BLOCKS) * 256 + threadIdx.x;
    if (i >= WBUF_N) return;
    const void* src; int local;
    if (i < OFF_WR0T) {                       // Wl0^T: out(j,k) <- in(k,j), in = 64x128
        const int j = i >> 6, k = i & 63;
        src = s0; local = k * 128 + j;
    } else if (i < OFF_WLT) {                 // Wr0^T
        const int t = i - OFF_WR0T, j = t >> 6, k = t & 63;
        src = s1; local = k * 128 + j;
    } else if (i < OFF_WRT) {                 // Wl^T: 11 x (out(j,k) <- in(k,j)), in = 128x128
        const int t = i - OFF_WLT, l = t >> 14, r = t & 16383, j = r >> 7, k = r & 127;
        src = s3; local = (l << 14) + k * 128 + j;
    } else if (i < OFF_B0) {                  // Wr^T
        const int t = i - OFF_WRT, l = t >> 14, r = t & 16383, j = r >> 7, k = r & 127;
        src = s4; local = (l << 14) + k * 128 + j;
    } else if (i < OFF_B) {
        src = s2; local = i - OFF_B0;         // b0
    } else if (i < OFF_HW) {
        src = s5; local = i - OFF_B;          // b
    } else if (i < OFF_HB) {
        src = s6; local = i - OFF_HW;         // head_W
    } else {
        src = s7; local = i - OFF_HB;         // head_b
    }
    wbuf[i] = m ? f2bf(((const float*)src)[local]) : ((const unsigned short*)src)[local];
}

// ---------- CSR build, round-18: two-level binned scatter ----------
// Old k_count+k_fill: 2 full ei reads + 800K random 2B stores -> 52MB HBM
// writeback (64B line per store) = 57us. New: fillA bins edges into 128
// coarse dst-buckets (512 nodes each) via LDS, writing packed (dst<<16|src)
// words COALESCED into fixed bucket regions (+ deg atomics fused = one ei
// read saved). fillB scatters per-bucket into a ~16KB csr window -> ~30x
// line reuse -> writeback ~ csr size. Intra-dst order was already
// nondeterministic (atomic races), so reordering is semantically free.
#define FA_EPB   8192                          // edges per fillA block
#define FA_BLKS  ((EDGES + FA_EPB - 1) / FA_EPB)   // 98
#define NBUCK    128                           // dst>>9 -> 0..97 used
#define BUCK_CAP 16384                         // slots per bucket region (max ~8.7K)

__global__ __launch_bounds__(256) void k_fillA(const int* __restrict__ ei,
                                               int* __restrict__ deg,
                                               int* __restrict__ bucketCur,
                                               unsigned int* __restrict__ packed) {
    __shared__ unsigned int pk[FA_EPB];        // 32 KB
    __shared__ int hist[NBUCK], lofs[NBUCK], lcur[NBUCK], gbase[NBUCK];
    const int t = threadIdx.x;
    for (int b = t; b < NBUCK; b += 256) hist[b] = 0;
    __syncthreads();
    const int e0 = blockIdx.x * FA_EPB;
    // pass 1: histogram + global degree count
    for (int i = 0; i < FA_EPB / 256; ++i) {
        const int e = e0 + i * 256 + t;
        if (e < EDGES) {
            const int d = ei[EDGES + e];
            if ((unsigned)d < NODES) {
                atomicAdd(&deg[d], 1);
                atomicAdd(&hist[d >> 9], 1);
            }
        }
    }
    __syncthreads();
    // exclusive scan of hist (wave 0: 2 elems/lane shfl scan)
    if (t < 64) {
        const int v0 = hist[2 * t], v1 = hist[2 * t + 1];
        int s = v0 + v1;
#pragma unroll
        for (int off = 1; off < 64; off <<= 1) {
            const int o = __shfl_up(s, off);
            if (t >= off) s += o;
        }
        const int excl = s - (v0 + v1);
        lofs[2 * t] = excl; lofs[2 * t + 1] = excl + v0;
        lcur[2 * t] = 0;    lcur[2 * t + 1] = 0;
    }
    __syncthreads();
    // pass 2: pack into LDS grouped by bucket (re-read ei; L2-hot)
    for (int i = 0; i < FA_EPB / 256; ++i) {
        const int e = e0 + i * 256 + t;
        if (e < EDGES) {
            const int d = ei[EDGES + e];
            if ((unsigned)d < NODES) {
                const int s = ei[e];
                const int b = d >> 9;
                const int pos = lofs[b] + atomicAdd(&lcur[b], 1);
                pk[pos] = ((unsigned)d << 16) | (unsigned)s;   // src < 65536
            }
        }
    }
    __syncthreads();
    // reserve contiguous global chunks per bucket
    if (t < NBUCK) {
        const int cnt = hist[t];
        gbase[t] = (cnt > 0) ? atomicAdd(&bucketCur[t], cnt) : 0;
    }
    __syncthreads();
    // coalesced copy-out: consecutive idx -> mostly-consecutive global slots
    const int total = lofs[NBUCK - 1] + hist[NBUCK - 1];
    for (int idx = t; idx < total; idx += 256) {
        const unsigned int v = pk[idx];
        const int b = (int)(v >> 16) >> 9;
        packed[(size_t)b * BUCK_CAP + gbase[b] + (idx - lofs[b])] = v;
    }
}

// fillB: per-bucket scatter into a narrow (~16KB) csr window.
__global__ __launch_bounds__(256) void k_fillB(const unsigned int* __restrict__ packed,
                                               const int* __restrict__ bucketCur,
                                               int* __restrict__ cursor,
                                               unsigned short* __restrict__ csr_src) {
    const int b = blockIdx.x >> 2, q = blockIdx.x & 3;
    const int cnt = bucketCur[b];
    const int s0 = (cnt * q) >> 2, s1 = (cnt * (q + 1)) >> 2;
    for (int i = s0 + threadIdx.x; i < s1; i += 256) {
        const unsigned int v = packed[(size_t)b * BUCK_CAP + i];
        const int d = (int)(v >> 16);
        const int p = atomicAdd(&cursor[d], 1);
        csr_src[p] = (unsigned short)(v & 0xffffu);
    }
}

// scan over PADDED degrees: p = (d+7) & ~7  (8-aligned row starts -> uint4
// index loads in the gather; pad slots point at the zero dummy row)
__global__ __launch_bounds__(1024) void k_scan_block(const int* __restrict__ deg,
                                                     int* __restrict__ tmp,
                                                     int* __restrict__ bsums) {
    __shared__ int s[1024];
    const int idx = blockIdx.x * 1024 + threadIdx.x;
    s[threadIdx.x] = (idx < NODES) ? ((deg[idx] + 7) & ~7) : 0;
    __syncthreads();
    for (int off = 1; off < 1024; off <<= 1) {
        int v = (threadIdx.x >= off) ? s[threadIdx.x - off] : 0;
        __syncthreads();
        s[threadIdx.x] += v;
        __syncthreads();
    }
    if (idx < NODES) tmp[idx] = s[threadIdx.x];
    if (threadIdx.x == 1023) bsums[blockIdx.x] = s[1023];
}

// wave-parallel exclusive scan of <=64 block sums (was 49-iter serial thread)
__global__ void k_scan_sums(int* __restrict__ bsums, int nb) {
    const int t = threadIdx.x;
    const int v = (t < nb) ? bsums[t] : 0;
    int s = v;
#pragma unroll
    for (int off = 1; off < 64; off <<= 1) {
        const int o = __shfl_up(s, off);
        if (t >= off) s += o;
    }
    if (t < nb) bsums[t] = s - v;
}

__global__ __launch_bounds__(1024) void k_scan_fin(const int* __restrict__ deg,
                                                   const int* __restrict__ tmp,
                                                   const int* __restrict__ bsums,
                                                   int* __restrict__ row_ptr,
                                                   int* __restrict__ cursor,
                                                   float* __restrict__ inv_deg,
                                                   unsigned short* __restrict__ csr_src) {
    const int idx = blockIdx.x * 1024 + threadIdx.x;
    if (idx >= NODES) return;
    const int incl = tmp[idx] + bsums[blockIdx.x];      // padded inclusive scan
    const int d = deg[idx];
    const int p = (d + 7) & ~7;
    const int start = incl - p;
    row_ptr[idx + 1] = incl;
    cursor[idx] = start;
    inv_deg[idx] = (d > 0) ? (1.0f / (float)d) : 0.0f;
    for (int i = d; i < p; ++i) csr_src[start + i] = (unsigned short)NODES;  // pad -> zero row
    if (idx == 0) row_ptr[0] = 0;
}

// ws-too-small sentinel: absmax will read ~(1000 + ws_MB)
__global__ __launch_bounds__(256) void k_ws_stamp(unsigned short* __restrict__ outp, float v) {
    const int t = blockIdx.x * 256 + threadIdx.x;
    if (t < NGRAPH * 2) outp[t] = f2bf(v);
}

// ---------- FUSED SAGE layer: out = act(mean_agg(h) @ Wl + h @ Wr + b) ----------
// Round-18: EXACT round-2 structure restored (proven best: 46.5us/layer).
// Post-mortem r1-r6: every latency/concurrency lever (waves 25->59%, reg
// ping-pong, waves_per_eu, LDS-ring async DMA) left dur/layer >= 46.5 at
// constant FETCH ~80MB -> the gather path is delivered-bandwidth-walled
// (~4.4 TB/s effective for 256B random rows; 8-XCD L2 duplication makes the
// ~80MB FETCH a structural floor for a random graph). Conv is AT its floor.
//
// Phase 1 (gather): lane = uint4 (16B), LPN = CH/8 lanes per node, 8-deep
// gather batches; padded CSR (8-aligned rows, pads -> zero dummy row NODES)
// gives one uint4 index load per 8-edge batch, prefetched one batch ahead.
// Phase 2 (MFMA): 4 waves; wave w owns cols n0 = w*32 over all 32 rows ->
// acc[2][2], 4 MFMAs/step, register double-buffer on A and B. Unified K-loop:
// steps 0..KC-1 = aggT@Wl (LDS), KC..2KC-1 = h@Wr (global).
// mfma_f32_16x16x32_bf16 layouts (m89/m120-verified):
//   A-frag: lane holds A[m=lane&15][k=quad*8+j]; B-frag: B[k=quad*8+j][n=lane&15]
//   C/D: lane reg r holds D[row=quad*4+r][col=lane&15]
// act: 0=none 1=relu 2=leaky(0.01)
template <int CH>
__global__ __launch_bounds__(256) void k_fused(const unsigned short* __restrict__ h,   // N x CH (+ zero row)
                                               const int* __restrict__ row_ptr,
                                               const unsigned short* __restrict__ csr_src,
                                               const float* __restrict__ inv_deg,
                                               const unsigned short* __restrict__ Wt1, // [128][CH]
                                               const unsigned short* __restrict__ Wt2, // [128][CH]
                                               const unsigned short* __restrict__ bias,
                                               unsigned short* __restrict__ outp,      // N x 128
                                               int act) {
    constexpr int LSTR = CH + 8;              // padded LDS stride (shorts)
    constexpr int LPN  = CH / 8;              // uint4 lanes per node (16 or 8)
    constexpr int NPW  = 64 / LPN;            // nodes per wave per iter (4 or 8)
    constexpr int NPB  = NPW * 4;             // nodes per block per iter (16 or 32)
    __shared__ unsigned short aggT[32][LSTR];

    const int wave = threadIdx.x >> 6;
    const int lane = threadIdx.x & 63;

    // ---- phase 1: mean-aggregate this block's 32 rows into LDS ----
    {
        const int sub = lane / LPN;
        const int cl  = lane % LPN;
        const uint4* hb = (const uint4*)h;
#pragma unroll
        for (int it = 0; it < 32 / NPB; ++it) {
            const int rl   = it * NPB + wave * NPW + sub;   // local row 0..31
            const int node = blockIdx.x * 32 + rl;
            float c0 = 0.f, c1 = 0.f, c2 = 0.f, c3 = 0.f;
            float c4 = 0.f, c5 = 0.f, c6 = 0.f, c7 = 0.f;
            if (node < NODES) {
                int e = row_ptr[node];
                const int e1 = row_ptr[node + 1];           // both 8-aligned
                uint4 iv;
                if (e < e1) iv = *(const uint4*)(csr_src + e);
                for (; e < e1; e += 8) {
                    uint4 u[8];
                    u[0] = hb[(size_t)(iv.x & 0xffffu) * LPN + cl];
                    u[1] = hb[(size_t)(iv.x >> 16)     * LPN + cl];
                    u[2] = hb[(size_t)(iv.y & 0xffffu) * LPN + cl];
                    u[3] = hb[(size_t)(iv.y >> 16)     * LPN + cl];
                    u[4] = hb[(size_t)(iv.z & 0xffffu) * LPN + cl];
                    u[5] = hb[(size_t)(iv.z >> 16)     * LPN + cl];
                    u[6] = hb[(size_t)(iv.w & 0xffffu) * LPN + cl];
                    u[7] = hb[(size_t)(iv.w >> 16)     * LPN + cl];
                    if (e + 8 < e1) iv = *(const uint4*)(csr_src + e + 8);  // prefetch
#pragma unroll
                    for (int j = 0; j < 8; ++j) {
                        c0 += bflo(u[j].x); c1 += bfhi(u[j].x);
                        c2 += bflo(u[j].y); c3 += bfhi(u[j].y);
                        c4 += bflo(u[j].z); c5 += bfhi(u[j].z);
                        c6 += bflo(u[j].w); c7 += bfhi(u[j].w);
                    }
                }
                const float inv = inv_deg[node];
                c0 *= inv; c1 *= inv; c2 *= inv; c3 *= inv;
                c4 *= inv; c5 *= inv; c6 *= inv; c7 *= inv;
            }
            uint4 o;     // rows >= NODES stay exactly zero (never NaN into MFMA)
            o.x = f2bf(c0) | ((unsigned int)f2bf(c1) << 16);
            o.y = f2bf(c2) | ((unsigned int)f2bf(c3) << 16);
            o.z = f2bf(c4) | ((unsigned int)f2bf(c5) << 16);
            o.w = f2bf(c6) | ((unsigned int)f2bf(c7) << 16);
            *(uint4*)&aggT[rl][cl * 8] = o;
        }
    }
    __syncthreads();

    // ---- phase 2: MFMA ----
    const int quad = lane >> 4;
    const int l16  = lane & 15;
    const int n0   = wave * 32;                // this wave's column origin
    const int m0   = blockIdx.x * 32;
    int rowH0 = m0 + l16;                      // global rows for the h@Wr half
    int rowH1 = m0 + 16 + l16;
    if (rowH0 >= NODES) rowH0 = NODES - 1;     // clamped rows feed MFMA, never stored
    if (rowH1 >= NODES) rowH1 = NODES - 1;

    constexpr int KC = CH / 32;
    constexpr int NS = 2 * KC;

    auto loadA = [&](int s, int rlocal, int growC) -> bf16x8 {
        if (s < KC)
            return *(const bf16x8*)&aggT[rlocal][s * 32 + quad * 8];
        return *(const bf16x8*)(h + (size_t)growC * CH + (s - KC) * 32 + quad * 8);
    };
    auto loadB = [&](int s, int nt) -> bf16x8 {
        const unsigned short* W = (s < KC) ? Wt1 : Wt2;
        const int kc = (s < KC) ? s : s - KC;
        return *(const bf16x8*)(W + (size_t)(n0 + nt * 16 + l16) * CH + kc * 32 + quad * 8);
    };

    f32x4 acc[2][2] = {};
    bf16x8 a0 = loadA(0, l16, rowH0);
    bf16x8 a1 = loadA(0, 16 + l16, rowH1);
    bf16x8 b[2];
#pragma unroll
    for (int nt = 0; nt < 2; ++nt) b[nt] = loadB(0, nt);

#pragma unroll
    for (int s = 0; s < NS; ++s) {
        bf16x8 na0, na1, nb[2];
        if (s + 1 < NS) {                      // issue next step's loads first
            na0 = loadA(s + 1, l16, rowH0);
            na1 = loadA(s + 1, 16 + l16, rowH1);
#pragma unroll
            for (int nt = 0; nt < 2; ++nt) nb[nt] = loadB(s + 1, nt);
        }
#pragma unroll
        for (int nt = 0; nt < 2; ++nt) {
            acc[0][nt] = __builtin_amdgcn_mfma_f32_16x16x32_bf16(a0, b[nt], acc[0][nt], 0, 0, 0);
            acc[1][nt] = __builtin_amdgcn_mfma_f32_16x16x32_bf16(a1, b[nt], acc[1][nt], 0, 0, 0);
        }
        if (s + 1 < NS) {
            a0 = na0; a1 = na1;
#pragma unroll
            for (int nt = 0; nt < 2; ++nt) b[nt] = nb[nt];
        }
    }

#pragma unroll
    for (int nt = 0; nt < 2; ++nt) {
        const float bj = bf2f(bias[n0 + nt * 16 + l16]);
#pragma unroll
        for (int mt = 0; mt < 2; ++mt) {
#pragma unroll
            for (int r = 0; r < 4; ++r) {
                const int row = m0 + mt * 16 + quad * 4 + r;
                if (row < NODES) {
                    float v = acc[mt][nt][r] + bj;
                    if (act == 1) v = fmaxf(v, 0.f);
                    else if (act == 2) v = v > 0.f ? v : 0.01f * v;
                    outp[(size_t)row * 128 + n0 + nt * 16 + l16] = f2bf(v);
                }
            }
        }
    }
}

// ---------- segmented global mean pool (batch_idx sorted) ----------
// 512 threads = 4 substreams x 128 channels; block covers 128 nodes; substream
// sg scans nodes n0+4i+sg (sorted within stream), flushing at graph transitions.
__global__ __launch_bounds__(512) void k_pool(const unsigned short* __restrict__ h,
                                              const int* __restrict__ batch,
                                              float* __restrict__ gsum,
                                              float* __restrict__ gcnt) {
    const int c = threadIdx.x & 127;
    const int sg = threadIdx.x >> 7;            // 0..3
    const int n0 = blockIdx.x * 128;
    float s = 0.f;
    int cnt = 0, gprev = -1;
#pragma unroll 4
    for (int i = 0; i < 32; ++i) {
        const int n = n0 + i * 4 + sg;
        if (n >= NODES) break;
        int g = batch[n];
        if ((unsigned)g >= NGRAPH) g = (gprev < 0) ? 0 : gprev;
        if (g != gprev) {
            if (gprev >= 0) {
                atomicAdd(&gsum[(size_t)gprev * 128 + c], s);
                if (c == 0) atomicAdd(&gcnt[gprev], (float)cnt);
            }
            s = 0.f; cnt = 0; gprev = g;
        }
        s += bf2f(h[(size_t)n * 128 + c]);
        cnt++;
    }
    if (gprev >= 0) {
        atomicAdd(&gsum[(size_t)gprev * 128 + c], s);
        if (c == 0) atomicAdd(&gcnt[gprev], (float)cnt);
    }
}

// ---------- head: out = pooled @ head_W + head_b (dtype-adaptive store) ----------
__global__ __launch_bounds__(256) void k_head(const float* __restrict__ gsum,
                                              const float* __restrict__ gcnt,
                                              const unsigned short* __restrict__ wbuf,
                                              const void* __restrict__ xin,
                                              void* __restrict__ outp) {
    const int m = detect_mode((const unsigned int*)xin);   // before any divergent return
    const int t = blockIdx.x * 256 + threadIdx.x;
    if (t >= NGRAPH * 2) return;
    const int g = t >> 1, o = t & 1;
    const float inv = 1.0f / fmaxf(gcnt[g], 1.0f);
    float s = bf2f(wbuf[OFF_HB + o]);
    for (int c = 0; c < 128; ++c)
        s += gsum[(size_t)g * 128 + c] * inv * bf2f(wbuf[OFF_HW + c * 2 + o]);
    if (m) ((float*)outp)[t] = s;
    else ((unsigned short*)outp)[t] = f2bf(s);
}

extern "C" void kernel_launch(void* const* d_in, const int* in_sizes, int n_in,
                              void* d_out, int out_size, void* d_ws, size_t ws_size,
                              hipStream_t stream) {
    const void* x     = d_in[0];
    const int*  ei    = (const int*)d_in[1];
    const int*  batch = (const int*)d_in[2];

    // ---- workspace carve-up (~38 MB; ws_size measured 256 MB in round 8) ----
    char* p = (char*)d_ws;
    auto alloc = [&](size_t bytes) -> void* {
        void* r = (void*)p;
        p += (bytes + 255) & ~(size_t)255;
        return r;
    };
    // +128 shorts: zero dummy row (index NODES) for padded-CSR gathers
    unsigned short* hA   = (unsigned short*)alloc(((size_t)NODES * 128 + 128) * 2);
    unsigned short* hB   = (unsigned short*)alloc(((size_t)NODES * 128 + 128) * 2);
    unsigned short* wbuf = (unsigned short*)alloc((size_t)(WBUF_N + 14) * 2);
    int*   deg     = (int*)alloc((size_t)NODES * 4);
    int*   tmp     = (int*)alloc((size_t)NODES * 4);
    int*   row_ptr = (int*)alloc((size_t)(NODES + 1) * 4);
    int*   cursor  = (int*)alloc((size_t)NODES * 4);
    float* inv_deg = (float*)alloc((size_t)NODES * 4);
    unsigned short* csr_src = (unsigned short*)alloc((size_t)(EDGES + 8 * NODES) * 2); // padded
    int*   bsums   = (int*)alloc(64 * 4);
    float* gsum    = (float*)alloc((size_t)NGRAPH * 128 * 4);
    float* gcnt    = (float*)alloc((size_t)NGRAPH * 4);
    int*   bucketCur = (int*)alloc(NBUCK * 4);
    unsigned int* packed = (unsigned int*)alloc((size_t)NBUCK * BUCK_CAP * 4);  // 8 MB
    const size_t need = (size_t)(p - (char*)d_ws);
    (void)in_sizes; (void)n_in; (void)out_size;

    if (ws_size < need) {
        k_ws_stamp<<<4, 256, 0, stream>>>((unsigned short*)d_out,
                                          1000.0f + (float)(ws_size >> 20));
        return;
    }

    // fused setup: x convert + zeroing (deg/gsum/gcnt/dummies/bucketCur) + weights
    k_setup<<<CVT_BLOCKS + ZERO_BLOCKS + W_BLOCKS, 256, 0, stream>>>(
        x, d_in[3], d_in[4], d_in[5], d_in[6], d_in[7], d_in[8], d_in[9], d_in[10],
        wbuf, hA, hB, deg, gsum, gcnt, bucketCur);

    // CSR build: binned two-pass scatter (deg count fused into fillA)
    const int nbScan = (NODES + 1023) / 1024;   // 49
    k_fillA<<<FA_BLKS, 256, 0, stream>>>(ei, deg, bucketCur, packed);
    k_scan_block<<<nbScan, 1024, 0, stream>>>(deg, tmp, bsums);
    k_scan_sums<<<1, 64, 0, stream>>>(bsums, nbScan);
    k_scan_fin<<<nbScan, 1024, 0, stream>>>(deg, tmp, bsums, row_ptr, cursor, inv_deg, csr_src);
    k_fillB<<<NBUCK * 4, 256, 0, stream>>>(packed, bucketCur, cursor, csr_src);

    const int gemmGrid = (NODES + 31) / 32;      // 1563 (32 rows per block, r2-best)

    // conv 0: 64 -> 128, ReLU. x in hA (N x 64); fused agg+GEMM -> hB.
    k_fused<64><<<gemmGrid, 256, 0, stream>>>(hA, row_ptr, csr_src, inv_deg,
                                              wbuf + OFF_WL0T, wbuf + OFF_WR0T,
                                              wbuf + OFF_B0, hB, 1);

    // convs 1..11: 128 -> 128, ping-pong hB <-> hA
    unsigned short* cur = hB;
    unsigned short* nxt = hA;
    for (int i = 0; i < 11; ++i) {
        const int ci = i + 1;
        const int act = ((ci + 1) % 4 != 0) ? 1 : ((ci == 3 || ci == 7) ? 2 : 0);
        k_fused<128><<<gemmGrid, 256, 0, stream>>>(cur, row_ptr, csr_src, inv_deg,
                                                   wbuf + OFF_WLT + (size_t)i * 128 * 128,
                                                   wbuf + OFF_WRT + (size_t)i * 128 * 128,
                                                   wbuf + OFF_B + (size_t)i * 128,
                                                   nxt, act);
        unsigned short* t = cur; cur = nxt; nxt = t;
    }

    // pool + head
    k_pool<<<(NODES + 127) / 128, 512, 0, stream>>>(cur, batch, gsum, gcnt);
    k_head<<<(NGRAPH * 2 + 255) / 256, 256, 0, stream>>>(gsum, gcnt, wbuf, x, d_out);
}

// Round 8
// 688.032 us; speedup vs baseline: 1.6391x; 1.0064x over previous
//
#include <hip/hip_runtime.h>

// Problem constants (from reference)
#define NODES  50000
#define EDGES  800000
#define NGRAPH 512

// short-element offsets inside the canonical bf16 weight buffer (wbuf).
// All W matrices are stored TRANSPOSED: Wt[j][k] (128 rows x CH cols), so the
// MFMA B-fragment (8 consecutive k for fixed j) is a contiguous 16B load.
#define OFF_WL0T 0         // [128][64]
#define OFF_WR0T 8192      // [128][64]
#define OFF_WLT  16384     // 11 x [128][128]
#define OFF_WRT  196608    // 11 x [128][128]
#define OFF_B0   376832    // 128
#define OFF_B    376960    // 11*128
#define OFF_HW   378368    // 128*2 (row-major, as input)
#define OFF_HB   378624    // 2
#define WBUF_N   378626

typedef __attribute__((ext_vector_type(8))) short bf16x8;
typedef __attribute__((ext_vector_type(4))) float f32x4;

// ---------- bf16 helpers (internal compute fp32) ----------
__device__ __forceinline__ float bflo(unsigned int u) {
    union { unsigned int i; float f; } c; c.i = u << 16; return c.f;
}
__device__ __forceinline__ float bfhi(unsigned int u) {
    union { unsigned int i; float f; } c; c.i = u & 0xffff0000u; return c.f;
}
__device__ __forceinline__ float bf2f(unsigned short u) {
    union { unsigned int i; float f; } c; c.i = ((unsigned int)u) << 16; return c.f;
}
__device__ __forceinline__ unsigned short f2bf(float f) {
    union { float f; unsigned int i; } c; c.f = f;
    unsigned int u = c.i;
    u = (u + 0x7fffu + ((u >> 16) & 1u)) >> 16;   // round-to-nearest-even
    return (unsigned short)u;
}

// ---------- block-local dtype sniff: bf16 inputs -> 0, fp32 inputs -> 1 ----------
// 64-lane shuffle reduction: MUST be called by ALL lanes of a wave, i.e. before
// any divergent early-return (round-10 bug).
__device__ __forceinline__ int detect_mode(const unsigned int* __restrict__ xu) {
    int bad = 0;
    for (int i = (threadIdx.x & 63); i < 512; i += 64) {
        const unsigned int u = xu[i];
        if (!(fabsf(bflo(u)) < 1e4f)) bad++;   // also catches NaN
        if (!(fabsf(bfhi(u)) < 1e4f)) bad++;
    }
#pragma unroll
    for (int off = 32; off; off >>= 1) bad += __shfl_down(bad, off);
    bad = __shfl(bad, 0);
    return (bad > 16) ? 1 : 0;
}

// ---------- fused setup: x-convert + zeroing + weight repack (range dispatch) ----
// Dummy row trick: CSR is padded per-node to a multiple of 8 with index =
// NODES, pointing at an all-zero feature row so padded gathers add exactly
// 0.0f. Zero list: deg, gsum, gcnt, hA64 dummy, hA128 dummy, hB128 dummy,
// bucketCur (binned CSR build).
#define CVT_BLOCKS 1563    // ceil(NODES*64/8 / 256)
#define ZB_GSUM  (NODES)
#define ZB_GCNT  (NODES + NGRAPH * 128)
#define ZB_D64   (NODES + NGRAPH * 128 + NGRAPH)
#define ZB_D128A (ZB_D64 + 32)
#define ZB_D128B (ZB_D64 + 96)
#define ZB_BCUR  (ZB_D64 + 160)
#define ZERO_WORDS (ZB_BCUR + 128)
#define ZERO_BLOCKS ((ZERO_WORDS + 255) / 256)     // 455
#define W_BLOCKS ((WBUF_N + 255) / 256)            // 1480
__global__ __launch_bounds__(256) void k_setup(const void* __restrict__ xin,
                                               const void* s0, const void* s1, const void* s2,
                                               const void* s3, const void* s4, const void* s5,
                                               const void* s6, const void* s7,
                                               unsigned short* __restrict__ wbuf,
                                               unsigned short* __restrict__ hx,
                                               unsigned short* __restrict__ hB,
                                               int* __restrict__ deg,
                                               float* __restrict__ gsum,
                                               float* __restrict__ gcnt,
                                               int* __restrict__ bucketCur) {
    if (blockIdx.x < CVT_BLOCKS) {            // ---- x -> bf16 canonical (N x 64)
        const int m = detect_mode((const unsigned int*)xin);   // before divergent return
        const int i = blockIdx.x * 256 + threadIdx.x;   // groups of 8 elements
        if (i >= NODES * 64 / 8) return;
        if (m == 0) {
            ((uint4*)hx)[i] = ((const uint4*)xin)[i];
        } else {
            const float4* f = (const float4*)xin;
            const float4 a = f[2 * i], b = f[2 * i + 1];
            const unsigned int p0 = f2bf(a.x) | ((unsigned int)f2bf(a.y) << 16);
            const unsigned int p1 = f2bf(a.z) | ((unsigned int)f2bf(a.w) << 16);
            const unsigned int p2 = f2bf(b.x) | ((unsigned int)f2bf(b.y) << 16);
            const unsigned int p3 = f2bf(b.z) | ((unsigned int)f2bf(b.w) << 16);
            ((uint4*)hx)[i] = make_uint4(p0, p1, p2, p3);
        }
        return;
    }
    if (blockIdx.x < CVT_BLOCKS + ZERO_BLOCKS) {   // ---- zeroing tail
        const int i = (blockIdx.x - CVT_BLOCKS) * 256 + threadIdx.x;
        if (i < ZB_GSUM) deg[i] = 0;
        else if (i < ZB_GCNT) gsum[i - ZB_GSUM] = 0.f;
        else if (i < ZB_D64) gcnt[i - ZB_GCNT] = 0.f;
        else if (i < ZB_D128A)
            ((unsigned int*)(hx + (size_t)NODES * 64))[i - ZB_D64] = 0u;
        else if (i < ZB_D128B)
            ((unsigned int*)(hx + (size_t)NODES * 128))[i - ZB_D128A] = 0u;
        else if (i < ZB_BCUR)
            ((unsigned int*)(hB + (size_t)NODES * 128))[i - ZB_D128B] = 0u;
        else if (i < ZERO_WORDS)
            bucketCur[i - ZB_BCUR] = 0;
        return;
    }
    // ---- weight repack (mode sniffed block-locally)
    const int m = detect_mode((const unsigned int*)xin);   // before any divergent return
    const int i = (blockIdx.x - CVT_BLOCKS - ZERO_BLOCKS) * 256 + threadIdx.x;
    if (i >= WBUF_N) return;
    const void* src; int local;
    if (i < OFF_WR0T) {                       // Wl0^T: out(j,k) <- in(k,j), in = 64x128
        const int j = i >> 6, k = i & 63;
        src = s0; local = k * 128 + j;
    } else if (i < OFF_WLT) {                 // Wr0^T
        const int t = i - OFF_WR0T, j = t >> 6, k = t & 63;
        src = s1; local = k * 128 + j;
    } else if (i < OFF_WRT) {                 // Wl^T: 11 x (out(j,k) <- in(k,j)), in = 128x128
        const int t = i - OFF_WLT, l = t >> 14, r = t & 16383, j = r >> 7, k = r & 127;
        src = s3; local = (l << 14) + k * 128 + j;
    } else if (i < OFF_B0) {                  // Wr^T
        const int t = i - OFF_WRT, l = t >> 14, r = t & 16383, j = r >> 7, k = r & 127;
        src = s4; local = (l << 14) + k * 128 + j;
    } else if (i < OFF_B) {
        src = s2; local = i - OFF_B0;         // b0
    } else if (i < OFF_HW) {
        src = s5; local = i - OFF_B;          // b
    } else if (i < OFF_HB) {
        src = s6; local = i - OFF_HW;         // head_W
    } else {
        src = s7; local = i - OFF_HB;         // head_b
    }
    wbuf[i] = m ? f2bf(((const float*)src)[local]) : ((const unsigned short*)src)[local];
}

// ---------- CSR build: two-level binned scatter ----------
// Round-19 fix: round-7's fillA (FA_EPB=8192, grid 98) ran at Occ 3.7% --
// 60% of CUs idle, 1 block/CU elsewhere, atomic latency fully exposed
// (63us > old plain-scatter's 57us despite halved writeback). The work is
// ~10us of traffic; it needed PARALLELISM. FA_EPB=2048 -> grid 391, LDS
// 10.2KB/block (~12 blocks/CU schedulable). Per-block bucket chunks still
// avg 16 words = 64B = 1-2 lines -> line reuse retained vs naive scatter.
#define FA_EPB   2048                          // edges per fillA block
#define FA_BLKS  ((EDGES + FA_EPB - 1) / FA_EPB)   // 391
#define NBUCK    128                           // dst>>9 -> 0..97 used
#define BUCK_CAP 16384                         // slots per bucket region (max ~8.7K)

__global__ __launch_bounds__(256) void k_fillA(const int* __restrict__ ei,
                                               int* __restrict__ deg,
                                               int* __restrict__ bucketCur,
                                               unsigned int* __restrict__ packed) {
    __shared__ unsigned int pk[FA_EPB];        // 8 KB
    __shared__ int hist[NBUCK], lofs[NBUCK], lcur[NBUCK], gbase[NBUCK];
    const int t = threadIdx.x;
    for (int b = t; b < NBUCK; b += 256) hist[b] = 0;
    __syncthreads();
    const int e0 = blockIdx.x * FA_EPB;
    // pass 1: histogram + global degree count
    for (int i = 0; i < FA_EPB / 256; ++i) {
        const int e = e0 + i * 256 + t;
        if (e < EDGES) {
            const int d = ei[EDGES + e];
            if ((unsigned)d < NODES) {
                atomicAdd(&deg[d], 1);
                atomicAdd(&hist[d >> 9], 1);
            }
        }
    }
    __syncthreads();
    // exclusive scan of hist (wave 0: 2 elems/lane shfl scan)
    if (t < 64) {
        const int v0 = hist[2 * t], v1 = hist[2 * t + 1];
        int s = v0 + v1;
#pragma unroll
        for (int off = 1; off < 64; off <<= 1) {
            const int o = __shfl_up(s, off);
            if (t >= off) s += o;
        }
        const int excl = s - (v0 + v1);
        lofs[2 * t] = excl; lofs[2 * t + 1] = excl + v0;
        lcur[2 * t] = 0;    lcur[2 * t + 1] = 0;
    }
    __syncthreads();
    // pass 2: pack into LDS grouped by bucket (re-read ei; L2-hot)
    for (int i = 0; i < FA_EPB / 256; ++i) {
        const int e = e0 + i * 256 + t;
        if (e < EDGES) {
            const int d = ei[EDGES + e];
            if ((unsigned)d < NODES) {
                const int s = ei[e];
                const int b = d >> 9;
                const int pos = lofs[b] + atomicAdd(&lcur[b], 1);
                pk[pos] = ((unsigned)d << 16) | (unsigned)s;   // src < 65536
            }
        }
    }
    __syncthreads();
    // reserve contiguous global chunks per bucket
    if (t < NBUCK) {
        const int cnt = hist[t];
        gbase[t] = (cnt > 0) ? atomicAdd(&bucketCur[t], cnt) : 0;
    }
    __syncthreads();
    // coalesced copy-out: consecutive idx -> mostly-consecutive global slots
    const int total = lofs[NBUCK - 1] + hist[NBUCK - 1];
    for (int idx = t; idx < total; idx += 256) {
        const unsigned int v = pk[idx];
        const int b = (int)(v >> 16) >> 9;
        packed[(size_t)b * BUCK_CAP + gbase[b] + (idx - lofs[b])] = v;
    }
}

// fillB: per-bucket scatter into a narrow (~16KB) csr window.
__global__ __launch_bounds__(256) void k_fillB(const unsigned int* __restrict__ packed,
                                               const int* __restrict__ bucketCur,
                                               int* __restrict__ cursor,
                                               unsigned short* __restrict__ csr_src) {
    const int b = blockIdx.x >> 3, q = blockIdx.x & 7;
    const int cnt = bucketCur[b];
    const int s0 = (cnt * q) >> 3, s1 = (cnt * (q + 1)) >> 3;
    for (int i = s0 + threadIdx.x; i < s1; i += 256) {
        const unsigned int v = packed[(size_t)b * BUCK_CAP + i];
        const int d = (int)(v >> 16);
        const int p = atomicAdd(&cursor[d], 1);
        csr_src[p] = (unsigned short)(v & 0xffffu);
    }
}

// scan over PADDED degrees: p = (d+7) & ~7  (8-aligned row starts -> uint4
// index loads in the gather; pad slots point at the zero dummy row)
__global__ __launch_bounds__(1024) void k_scan_block(const int* __restrict__ deg,
                                                     int* __restrict__ tmp,
                                                     int* __restrict__ bsums) {
    __shared__ int s[1024];
    const int idx = blockIdx.x * 1024 + threadIdx.x;
    s[threadIdx.x] = (idx < NODES) ? ((deg[idx] + 7) & ~7) : 0;
    __syncthreads();
    for (int off = 1; off < 1024; off <<= 1) {
        int v = (threadIdx.x >= off) ? s[threadIdx.x - off] : 0;
        __syncthreads();
        s[threadIdx.x] += v;
        __syncthreads();
    }
    if (idx < NODES) tmp[idx] = s[threadIdx.x];
    if (threadIdx.x == 1023) bsums[blockIdx.x] = s[1023];
}

// wave-parallel exclusive scan of <=64 block sums
__global__ void k_scan_sums(int* __restrict__ bsums, int nb) {
    const int t = threadIdx.x;
    const int v = (t < nb) ? bsums[t] : 0;
    int s = v;
#pragma unroll
    for (int off = 1; off < 64; off <<= 1) {
        const int o = __shfl_up(s, off);
        if (t >= off) s += o;
    }
    if (t < nb) bsums[t] = s - v;
}

__global__ __launch_bounds__(1024) void k_scan_fin(const int* __restrict__ deg,
                                                   const int* __restrict__ tmp,
                                                   const int* __restrict__ bsums,
                                                   int* __restrict__ row_ptr,
                                                   int* __restrict__ cursor,
                                                   float* __restrict__ inv_deg,
                                                   unsigned short* __restrict__ csr_src) {
    const int idx = blockIdx.x * 1024 + threadIdx.x;
    if (idx >= NODES) return;
    const int incl = tmp[idx] + bsums[blockIdx.x];      // padded inclusive scan
    const int d = deg[idx];
    const int p = (d + 7) & ~7;
    const int start = incl - p;
    row_ptr[idx + 1] = incl;
    cursor[idx] = start;
    inv_deg[idx] = (d > 0) ? (1.0f / (float)d) : 0.0f;
    for (int i = d; i < p; ++i) csr_src[start + i] = (unsigned short)NODES;  // pad -> zero row
    if (idx == 0) row_ptr[0] = 0;
}

// ws-too-small sentinel: absmax will read ~(1000 + ws_MB)
__global__ __launch_bounds__(256) void k_ws_stamp(unsigned short* __restrict__ outp, float v) {
    const int t = blockIdx.x * 256 + threadIdx.x;
    if (t < NGRAPH * 2) outp[t] = f2bf(v);
}

// ---------- FUSED SAGE layer: out = act(mean_agg(h) @ Wl + h @ Wr + b) ----------
// Round-2 structure (proven best: 46.5us/layer). r1-r6 established: every
// latency/concurrency lever (waves 25->59%, reg ping-pong, waves_per_eu,
// LDS-ring async DMA) left dur/layer >= 46.5 at constant FETCH ~80MB -> the
// gather path is delivered-bandwidth-walled (~4.4 TB/s effective for 256B
// random rows; 8-XCD L2 duplication makes ~80MB FETCH the structural floor
// for a random graph). Conv is AT its floor.
//
// Phase 1 (gather): lane = uint4 (16B), LPN = CH/8 lanes per node, 8-deep
// gather batches; padded CSR (8-aligned rows, pads -> zero dummy row NODES)
// gives one uint4 index load per 8-edge batch, prefetched one batch ahead.
// Phase 2 (MFMA): 4 waves; wave w owns cols n0 = w*32 over all 32 rows ->
// acc[2][2], 4 MFMAs/step, register double-buffer on A and B. Unified K-loop:
// steps 0..KC-1 = aggT@Wl (LDS), KC..2KC-1 = h@Wr (global).
// mfma_f32_16x16x32_bf16 layouts (m89/m120-verified):
//   A-frag: lane holds A[m=lane&15][k=quad*8+j]; B-frag: B[k=quad*8+j][n=lane&15]
//   C/D: lane reg r holds D[row=quad*4+r][col=lane&15]
// act: 0=none 1=relu 2=leaky(0.01)
template <int CH>
__global__ __launch_bounds__(256) void k_fused(const unsigned short* __restrict__ h,   // N x CH (+ zero row)
                                               const int* __restrict__ row_ptr,
                                               const unsigned short* __restrict__ csr_src,
                                               const float* __restrict__ inv_deg,
                                               const unsigned short* __restrict__ Wt1, // [128][CH]
                                               const unsigned short* __restrict__ Wt2, // [128][CH]
                                               const unsigned short* __restrict__ bias,
                                               unsigned short* __restrict__ outp,      // N x 128
                                               int act) {
    constexpr int LSTR = CH + 8;              // padded LDS stride (shorts)
    constexpr int LPN  = CH / 8;              // uint4 lanes per node (16 or 8)
    constexpr int NPW  = 64 / LPN;            // nodes per wave per iter (4 or 8)
    constexpr int NPB  = NPW * 4;             // nodes per block per iter (16 or 32)
    __shared__ unsigned short aggT[32][LSTR];

    const int wave = threadIdx.x >> 6;
    const int lane = threadIdx.x & 63;

    // ---- phase 1: mean-aggregate this block's 32 rows into LDS ----
    {
        const int sub = lane / LPN;
        const int cl  = lane % LPN;
        const uint4* hb = (const uint4*)h;
#pragma unroll
        for (int it = 0; it < 32 / NPB; ++it) {
            const int rl   = it * NPB + wave * NPW + sub;   // local row 0..31
            const int node = blockIdx.x * 32 + rl;
            float c0 = 0.f, c1 = 0.f, c2 = 0.f, c3 = 0.f;
            float c4 = 0.f, c5 = 0.f, c6 = 0.f, c7 = 0.f;
            if (node < NODES) {
                int e = row_ptr[node];
                const int e1 = row_ptr[node + 1];           // both 8-aligned
                uint4 iv;
                if (e < e1) iv = *(const uint4*)(csr_src + e);
                for (; e < e1; e += 8) {
                    uint4 u[8];
                    u[0] = hb[(size_t)(iv.x & 0xffffu) * LPN + cl];
                    u[1] = hb[(size_t)(iv.x >> 16)     * LPN + cl];
                    u[2] = hb[(size_t)(iv.y & 0xffffu) * LPN + cl];
                    u[3] = hb[(size_t)(iv.y >> 16)     * LPN + cl];
                    u[4] = hb[(size_t)(iv.z & 0xffffu) * LPN + cl];
                    u[5] = hb[(size_t)(iv.z >> 16)     * LPN + cl];
                    u[6] = hb[(size_t)(iv.w & 0xffffu) * LPN + cl];
                    u[7] = hb[(size_t)(iv.w >> 16)     * LPN + cl];
                    if (e + 8 < e1) iv = *(const uint4*)(csr_src + e + 8);  // prefetch
#pragma unroll
                    for (int j = 0; j < 8; ++j) {
                        c0 += bflo(u[j].x); c1 += bfhi(u[j].x);
                        c2 += bflo(u[j].y); c3 += bfhi(u[j].y);
                        c4 += bflo(u[j].z); c5 += bfhi(u[j].z);
                        c6 += bflo(u[j].w); c7 += bfhi(u[j].w);
                    }
                }
                const float inv = inv_deg[node];
                c0 *= inv; c1 *= inv; c2 *= inv; c3 *= inv;
                c4 *= inv; c5 *= inv; c6 *= inv; c7 *= inv;
            }
            uint4 o;     // rows >= NODES stay exactly zero (never NaN into MFMA)
            o.x = f2bf(c0) | ((unsigned int)f2bf(c1) << 16);
            o.y = f2bf(c2) | ((unsigned int)f2bf(c3) << 16);
            o.z = f2bf(c4) | ((unsigned int)f2bf(c5) << 16);
            o.w = f2bf(c6) | ((unsigned int)f2bf(c7) << 16);
            *(uint4*)&aggT[rl][cl * 8] = o;
        }
    }
    __syncthreads();

    // ---- phase 2: MFMA ----
    const int quad = lane >> 4;
    const int l16  = lane & 15;
    const int n0   = wave * 32;                // this wave's column origin
    const int m0   = blockIdx.x * 32;
    int rowH0 = m0 + l16;                      // global rows for the h@Wr half
    int rowH1 = m0 + 16 + l16;
    if (rowH0 >= NODES) rowH0 = NODES - 1;     // clamped rows feed MFMA, never stored
    if (rowH1 >= NODES) rowH1 = NODES - 1;

    constexpr int KC = CH / 32;
    constexpr int NS = 2 * KC;

    auto loadA = [&](int s, int rlocal, int growC) -> bf16x8 {
        if (s < KC)
            return *(const bf16x8*)&aggT[rlocal][s * 32 + quad * 8];
        return *(const bf16x8*)(h + (size_t)growC * CH + (s - KC) * 32 + quad * 8);
    };
    auto loadB = [&](int s, int nt) -> bf16x8 {
        const unsigned short* W = (s < KC) ? Wt1 : Wt2;
        const int kc = (s < KC) ? s : s - KC;
        return *(const bf16x8*)(W + (size_t)(n0 + nt * 16 + l16) * CH + kc * 32 + quad * 8);
    };

    f32x4 acc[2][2] = {};
    bf16x8 a0 = loadA(0, l16, rowH0);
    bf16x8 a1 = loadA(0, 16 + l16, rowH1);
    bf16x8 b[2];
#pragma unroll
    for (int nt = 0; nt < 2; ++nt) b[nt] = loadB(0, nt);

#pragma unroll
    for (int s = 0; s < NS; ++s) {
        bf16x8 na0, na1, nb[2];
        if (s + 1 < NS) {                      // issue next step's loads first
            na0 = loadA(s + 1, l16, rowH0);
            na1 = loadA(s + 1, 16 + l16, rowH1);
#pragma unroll
            for (int nt = 0; nt < 2; ++nt) nb[nt] = loadB(s + 1, nt);
        }
#pragma unroll
        for (int nt = 0; nt < 2; ++nt) {
            acc[0][nt] = __builtin_amdgcn_mfma_f32_16x16x32_bf16(a0, b[nt], acc[0][nt], 0, 0, 0);
            acc[1][nt] = __builtin_amdgcn_mfma_f32_16x16x32_bf16(a1, b[nt], acc[1][nt], 0, 0, 0);
        }
        if (s + 1 < NS) {
            a0 = na0; a1 = na1;
#pragma unroll
            for (int nt = 0; nt < 2; ++nt) b[nt] = nb[nt];
        }
    }

#pragma unroll
    for (int nt = 0; nt < 2; ++nt) {
        const float bj = bf2f(bias[n0 + nt * 16 + l16]);
#pragma unroll
        for (int mt = 0; mt < 2; ++mt) {
#pragma unroll
            for (int r = 0; r < 4; ++r) {
                const int row = m0 + mt * 16 + quad * 4 + r;
                if (row < NODES) {
                    float v = acc[mt][nt][r] + bj;
                    if (act == 1) v = fmaxf(v, 0.f);
                    else if (act == 2) v = v > 0.f ? v : 0.01f * v;
                    outp[(size_t)row * 128 + n0 + nt * 16 + l16] = f2bf(v);
                }
            }
        }
    }
}

// ---------- segmented global mean pool (batch_idx sorted) ----------
// 512 threads = 4 substreams x 128 channels; block covers 128 nodes; substream
// sg scans nodes n0+4i+sg (sorted within stream), flushing at graph transitions.
__global__ __launch_bounds__(512) void k_pool(const unsigned short* __restrict__ h,
                                              const int* __restrict__ batch,
                                              float* __restrict__ gsum,
                                              float* __restrict__ gcnt) {
    const int c = threadIdx.x & 127;
    const int sg = threadIdx.x >> 7;            // 0..3
    const int n0 = blockIdx.x * 128;
    float s = 0.f;
    int cnt = 0, gprev = -1;
#pragma unroll 4
    for (int i = 0; i < 32; ++i) {
        const int n = n0 + i * 4 + sg;
        if (n >= NODES) break;
        int g = batch[n];
        if ((unsigned)g >= NGRAPH) g = (gprev < 0) ? 0 : gprev;
        if (g != gprev) {
            if (gprev >= 0) {
                atomicAdd(&gsum[(size_t)gprev * 128 + c], s);
                if (c == 0) atomicAdd(&gcnt[gprev], (float)cnt);
            }
            s = 0.f; cnt = 0; gprev = g;
        }
        s += bf2f(h[(size_t)n * 128 + c]);
        cnt++;
    }
    if (gprev >= 0) {
        atomicAdd(&gsum[(size_t)gprev * 128 + c], s);
        if (c == 0) atomicAdd(&gcnt[gprev], (float)cnt);
    }
}

// ---------- head: out = pooled @ head_W + head_b (dtype-adaptive store) ----------
__global__ __launch_bounds__(256) void k_head(const float* __restrict__ gsum,
                                              const float* __restrict__ gcnt,
                                              const unsigned short* __restrict__ wbuf,
                                              const void* __restrict__ xin,
                                              void* __restrict__ outp) {
    const int m = detect_mode((const unsigned int*)xin);   // before any divergent return
    const int t = blockIdx.x * 256 + threadIdx.x;
    if (t >= NGRAPH * 2) return;
    const int g = t >> 1, o = t & 1;
    const float inv = 1.0f / fmaxf(gcnt[g], 1.0f);
    float s = bf2f(wbuf[OFF_HB + o]);
    for (int c = 0; c < 128; ++c)
        s += gsum[(size_t)g * 128 + c] * inv * bf2f(wbuf[OFF_HW + c * 2 + o]);
    if (m) ((float*)outp)[t] = s;
    else ((unsigned short*)outp)[t] = f2bf(s);
}

extern "C" void kernel_launch(void* const* d_in, const int* in_sizes, int n_in,
                              void* d_out, int out_size, void* d_ws, size_t ws_size,
                              hipStream_t stream) {
    const void* x     = d_in[0];
    const int*  ei    = (const int*)d_in[1];
    const int*  batch = (const int*)d_in[2];

    // ---- workspace carve-up (~38 MB; ws_size measured 256 MB in round 8) ----
    char* p = (char*)d_ws;
    auto alloc = [&](size_t bytes) -> void* {
        void* r = (void*)p;
        p += (bytes + 255) & ~(size_t)255;
        return r;
    };
    // +128 shorts: zero dummy row (index NODES) for padded-CSR gathers
    unsigned short* hA   = (unsigned short*)alloc(((size_t)NODES * 128 + 128) * 2);
    unsigned short* hB   = (unsigned short*)alloc(((size_t)NODES * 128 + 128) * 2);
    unsigned short* wbuf = (unsigned short*)alloc((size_t)(WBUF_N + 14) * 2);
    int*   deg     = (int*)alloc((size_t)NODES * 4);
    int*   tmp     = (int*)alloc((size_t)NODES * 4);
    int*   row_ptr = (int*)alloc((size_t)(NODES + 1) * 4);
    int*   cursor  = (int*)alloc((size_t)NODES * 4);
    float* inv_deg = (float*)alloc((size_t)NODES * 4);
    unsigned short* csr_src = (unsigned short*)alloc((size_t)(EDGES + 8 * NODES) * 2); // padded
    int*   bsums   = (int*)alloc(64 * 4);
    float* gsum    = (float*)alloc((size_t)NGRAPH * 128 * 4);
    float* gcnt    = (float*)alloc((size_t)NGRAPH * 4);
    int*   bucketCur = (int*)alloc(NBUCK * 4);
    unsigned int* packed = (unsigned int*)alloc((size_t)NBUCK * BUCK_CAP * 4);  // 8 MB
    const size_t need = (size_t)(p - (char*)d_ws);
    (void)in_sizes; (void)n_in; (void)out_size;

    if (ws_size < need) {
        k_ws_stamp<<<4, 256, 0, stream>>>((unsigned short*)d_out,
                                          1000.0f + (float)(ws_size >> 20));
        return;
    }

    // fused setup: x convert + zeroing (deg/gsum/gcnt/dummies/bucketCur) + weights
    k_setup<<<CVT_BLOCKS + ZERO_BLOCKS + W_BLOCKS, 256, 0, stream>>>(
        x, d_in[3], d_in[4], d_in[5], d_in[6], d_in[7], d_in[8], d_in[9], d_in[10],
        wbuf, hA, hB, deg, gsum, gcnt, bucketCur);

    // CSR build: binned two-pass scatter (deg count fused into fillA)
    const int nbScan = (NODES + 1023) / 1024;   // 49
    k_fillA<<<FA_BLKS, 256, 0, stream>>>(ei, deg, bucketCur, packed);
    k_scan_block<<<nbScan, 1024, 0, stream>>>(deg, tmp, bsums);
    k_scan_sums<<<1, 64, 0, stream>>>(bsums, nbScan);
    k_scan_fin<<<nbScan, 1024, 0, stream>>>(deg, tmp, bsums, row_ptr, cursor, inv_deg, csr_src);
    k_fillB<<<NBUCK * 8, 256, 0, stream>>>(packed, bucketCur, cursor, csr_src);

    const int gemmGrid = (NODES + 31) / 32;      // 1563 (32 rows per block, r2-best)

    // conv 0: 64 -> 128, ReLU. x in hA (N x 64); fused agg+GEMM -> hB.
    k_fused<64><<<gemmGrid, 256, 0, stream>>>(hA, row_ptr, csr_src, inv_deg,
                                              wbuf + OFF_WL0T, wbuf + OFF_WR0T,
                                              wbuf + OFF_B0, hB, 1);

    // convs 1..11: 128 -> 128, ping-pong hB <-> hA
    unsigned short* cur = hB;
    unsigned short* nxt = hA;
    for (int i = 0; i < 11; ++i) {
        const int ci = i + 1;
        const int act = ((ci + 1) % 4 != 0) ? 1 : ((ci == 3 || ci == 7) ? 2 : 0);
        k_fused<128><<<gemmGrid, 256, 0, stream>>>(cur, row_ptr, csr_src, inv_deg,
                                                   wbuf + OFF_WLT + (size_t)i * 128 * 128,
                                                   wbuf + OFF_WRT + (size_t)i * 128 * 128,
                                                   wbuf + OFF_B + (size_t)i * 128,
                                                   nxt, act);
        unsigned short* t = cur; cur = nxt; nxt = t;
    }

    // pool + head
    k_pool<<<(NODES + 127) / 128, 512, 0, stream>>>(cur, batch, gsum, gcnt);
    k_head<<<(NGRAPH * 2 + 255) / 256, 256, 0, stream>>>(gsum, gcnt, wbuf, x, d_out);
}